// Round 4
// baseline (791.351 us; speedup 1.0000x reference)
//
#include <hip/hip_runtime.h>
#include <hip/hip_bf16.h>

// Problem constants (fixed by reference)
constexpr int NN = 100000;   // nodes
constexpr int NE = 3200000;  // edges
constexpr int ROWS_PER_BUK = 8;
constexpr int NBUK = NN / ROWS_PER_BUK;          // 12500
constexpr int SCAN_PER_T = (NBUK + 255) / 256;   // 49

__device__ __forceinline__ unsigned short f2bf(float f) {
    unsigned int u = __float_as_uint(f);
    unsigned int r = (u + 0x7fffu + ((u >> 16) & 1u)) >> 16;   // RNE
    return (unsigned short)r;
}

// ---------------- GEMM1: xw1 = bf16(x @ W1)  [NN,128]x[128,128] ----------------
__global__ __launch_bounds__(256) void k_gemm1(const float* __restrict__ x,
                                               const float* __restrict__ W,
                                               unsigned short* __restrict__ y) {
    __shared__ float ws_[128 * 128];   // 64 KB: whole W1
    __shared__ float xs[8][128];       // 8 staged rows
    const int t = threadIdx.x;
    for (int i = t; i < 128 * 128; i += 256) ws_[i] = W[i];

    const int rowg = t >> 5;          // 0..7 (row within sub-tile)
    const int cq   = (t & 31) * 4;    // 4 output cols
    const int row0 = blockIdx.x * 32;

    for (int rs = 0; rs < 32; rs += 8) {
        __syncthreads();
        {   // stage 8 rows (1024 floats) as 256 float4s
            const int r  = t >> 5;
            const int c4 = (t & 31) * 4;
            const int row = row0 + rs + r;
            float4 val = (row < NN) ? *(const float4*)(x + row * 128 + c4)
                                    : make_float4(0.f, 0.f, 0.f, 0.f);
            *(float4*)(&xs[r][c4]) = val;
        }
        __syncthreads();
        float4 acc = make_float4(0.f, 0.f, 0.f, 0.f);
#pragma unroll
        for (int k = 0; k < 128; ++k) {
            const float xv = xs[rowg][k];
            const float4 wv = *(const float4*)(&ws_[k * 128 + cq]);
            acc.x = fmaf(xv, wv.x, acc.x);
            acc.y = fmaf(xv, wv.y, acc.y);
            acc.z = fmaf(xv, wv.z, acc.z);
            acc.w = fmaf(xv, wv.w, acc.w);
        }
        const int row = row0 + rs + rowg;
        if (row < NN) {
            ushort4 o;
            o.x = f2bf(acc.x); o.y = f2bf(acc.y);
            o.z = f2bf(acc.z); o.w = f2bf(acc.w);
            *(ushort4*)(y + row * 128 + cq) = o;   // 8B store
        }
    }
}

// ---------------- CSR build: 2-level bucket scatter ----------------
// bucket b = rows [8b, 8b+8). tmp record: x = (lrow<<17)|col, y = val bits.
__global__ __launch_bounds__(256) void k_bhist(const int4* __restrict__ erow4,
                                               int* __restrict__ bcnt) {
    const int i = blockIdx.x * 256 + threadIdx.x;
    if (i < NE / 4) {
        const int4 r = erow4[i];
        atomicAdd(&bcnt[r.x >> 3], 1);
        atomicAdd(&bcnt[r.y >> 3], 1);
        atomicAdd(&bcnt[r.z >> 3], 1);
        atomicAdd(&bcnt[r.w >> 3], 1);
    }
}

__global__ __launch_bounds__(256) void k_bscan(const int* __restrict__ bcnt,
                                               int* __restrict__ boff,
                                               int* __restrict__ bcur) {
    __shared__ int sd[256];
    const int t = threadIdx.x;
    const int i0 = t * SCAN_PER_T;
    int s = 0;
    for (int j = 0; j < SCAN_PER_T; ++j) {
        const int idx = i0 + j;
        if (idx < NBUK) s += bcnt[idx];
    }
    sd[t] = s;
    __syncthreads();
    for (int off = 1; off < 256; off <<= 1) {
        int a = sd[t];
        int b = (t >= off) ? sd[t - off] : 0;
        __syncthreads();
        sd[t] = a + b;
        __syncthreads();
    }
    int run = sd[t] - s;   // exclusive base for this thread's range
    for (int j = 0; j < SCAN_PER_T; ++j) {
        const int idx = i0 + j;
        if (idx < NBUK) {
            const int v = bcnt[idx];
            boff[idx] = run;
            bcur[idx] = run;
            run += v;
        }
    }
    if (t == 255) boff[NBUK] = run;   // = NE
}

__global__ __launch_bounds__(256) void k_bscatter(const int4* __restrict__ erow4,
                                                  const int4* __restrict__ ecol4,
                                                  const float4* __restrict__ eval4,
                                                  int* __restrict__ bcur,
                                                  uint2* __restrict__ tmp) {
    const int i = blockIdx.x * 256 + threadIdx.x;
    if (i < NE / 4) {
        const int4 r = erow4[i];
        const int4 c = ecol4[i];
        const float4 v = eval4[i];
        int p;
        p = atomicAdd(&bcur[r.x >> 3], 1);
        tmp[p] = make_uint2(((unsigned)(r.x & 7) << 17) | (unsigned)c.x, __float_as_uint(v.x));
        p = atomicAdd(&bcur[r.y >> 3], 1);
        tmp[p] = make_uint2(((unsigned)(r.y & 7) << 17) | (unsigned)c.y, __float_as_uint(v.y));
        p = atomicAdd(&bcur[r.z >> 3], 1);
        tmp[p] = make_uint2(((unsigned)(r.z & 7) << 17) | (unsigned)c.z, __float_as_uint(v.z));
        p = atomicAdd(&bcur[r.w >> 3], 1);
        tmp[p] = make_uint2(((unsigned)(r.w & 7) << 17) | (unsigned)c.w, __float_as_uint(v.w));
    }
}

// one workgroup per bucket: exact row_start + within-bucket reorder (L2-local)
__global__ __launch_bounds__(256) void k_bfinal(const uint2* __restrict__ tmp,
                                                const int* __restrict__ boff,
                                                uint2* __restrict__ recs,
                                                int* __restrict__ row_start) {
    __shared__ int cnt8[8];
    __shared__ int cur8[8];
    const int b = blockIdx.x;
    const int t = threadIdx.x;
    const int base = boff[b];
    const int n = boff[b + 1] - base;
    if (t < 8) cnt8[t] = 0;
    __syncthreads();
    for (int i = t; i < n; i += 256)
        atomicAdd(&cnt8[tmp[base + i].x >> 17], 1);
    __syncthreads();
    if (t == 0) {
        int run = 0;
        for (int r = 0; r < 8; ++r) {
            const int c = cnt8[r];
            cur8[r] = run;
            row_start[b * 8 + r] = base + run;
            run += c;
        }
    }
    __syncthreads();
    for (int i = t; i < n; i += 256) {
        const uint2 rc = tmp[base + i];
        const int lr = rc.x >> 17;
        const int pos = base + atomicAdd(&cur8[lr], 1);
        recs[pos] = make_uint2(rc.x & 0x1FFFFu, rc.y);
    }
    if (b == 0 && t == 0) row_start[NN] = NE;
}

// ---------------- SpMM1 + bias + ReLU: h = relu(A @ xw1 + b1) ----------------
// xw1 is bf16 [NN,128]: row = 64 uints (2 feats each). Lane handles feats 2*lane, 2*lane+1.
__global__ __launch_bounds__(256) void k_spmm1(const unsigned int* __restrict__ xw1u,
                                               const int* __restrict__ row_start,
                                               const uint2* __restrict__ recs,
                                               const float* __restrict__ b1,
                                               float* __restrict__ h) {
    const int wid = (blockIdx.x * 256 + threadIdx.x) >> 6;   // one wave per node
    const int lane = threadIdx.x & 63;
    if (wid >= NN) return;
    const int s = row_start[wid], e = row_start[wid + 1];
    float2 acc = make_float2(0.f, 0.f);
    for (int base = s; base < e; base += 64) {
        const int n = min(64, e - base);
        uint2 rv = make_uint2(0u, 0u);
        if (lane < n) rv = recs[base + lane];
        int j = 0;
        for (; j + 2 <= n; j += 2) {
            const int c0 = __shfl((int)rv.x, j), c1 = __shfl((int)rv.x, j + 1);
            const float v0 = __uint_as_float((unsigned int)__shfl((int)rv.y, j));
            const float v1 = __uint_as_float((unsigned int)__shfl((int)rv.y, j + 1));
            const unsigned int u0 = xw1u[c0 * 64 + lane];
            const unsigned int u1 = xw1u[c1 * 64 + lane];
            acc.x = fmaf(v0, __uint_as_float(u0 << 16), acc.x);
            acc.y = fmaf(v0, __uint_as_float(u0 & 0xffff0000u), acc.y);
            acc.x = fmaf(v1, __uint_as_float(u1 << 16), acc.x);
            acc.y = fmaf(v1, __uint_as_float(u1 & 0xffff0000u), acc.y);
        }
        if (j < n) {
            const int c0 = __shfl((int)rv.x, j);
            const float v0 = __uint_as_float((unsigned int)__shfl((int)rv.y, j));
            const unsigned int u0 = xw1u[c0 * 64 + lane];
            acc.x = fmaf(v0, __uint_as_float(u0 << 16), acc.x);
            acc.y = fmaf(v0, __uint_as_float(u0 & 0xffff0000u), acc.y);
        }
    }
    const float2 bb = *(const float2*)(b1 + (lane << 1));
    acc.x = fmaxf(acc.x + bb.x, 0.f);
    acc.y = fmaxf(acc.y + bb.y, 0.f);
    *(float2*)(h + wid * 128 + (lane << 1)) = acc;
}

// ---------------- GEMM2: hw4 = bf16(h @ W4)  [NN,128]x[128,16] ----------------
__global__ __launch_bounds__(256) void k_gemm2(const float* __restrict__ h,
                                               const float* __restrict__ W4,
                                               unsigned short* __restrict__ y) {
    __shared__ float w4s[128 * 16];
    __shared__ float hs[16 * 132];   // padded
    const int t = threadIdx.x;
    for (int i = t; i < 128 * 16; i += 256) w4s[i] = W4[i];
    const int row0 = blockIdx.x * 16;
    for (int idx4 = t; idx4 < 512; idx4 += 256) {   // 512 float4s = 16 rows
        const int r = idx4 >> 5;
        const int c4 = (idx4 & 31) * 4;
        const int row = row0 + r;
        float4 v = (row < NN) ? *(const float4*)(h + row * 128 + c4)
                              : make_float4(0.f, 0.f, 0.f, 0.f);
        *(float4*)(&hs[r * 132 + c4]) = v;
    }
    __syncthreads();
    const int r = t >> 4, c = t & 15;
    float acc = 0.f;
#pragma unroll
    for (int k = 0; k < 128; ++k) acc = fmaf(hs[r * 132 + k], w4s[k * 16 + c], acc);
    const int row = row0 + r;
    if (row < NN) y[row * 16 + c] = f2bf(acc);
}

// ---------------- SpMM2 + bias + log_softmax ----------------
// hw4 is bf16 [NN,16] = 32B rows (3.2 MB: mostly L2-resident)
__global__ __launch_bounds__(256) void k_spmm2(const __hip_bfloat16* __restrict__ hw4,
                                               const int* __restrict__ row_start,
                                               const uint2* __restrict__ recs,
                                               const float* __restrict__ b4,
                                               float* __restrict__ out) {
    const int wid = (blockIdx.x * 256 + threadIdx.x) >> 6;   // one wave per node
    const int lane = threadIdx.x & 63;
    if (wid >= NN) return;
    const int f = lane & 15, g = lane >> 4;   // 4 edges in parallel
    const int s = row_start[wid], e = row_start[wid + 1];
    float acc = 0.f;
    for (int base = s + g; base < e; base += 4) {
        const uint2 rv = recs[base];
        const int c = (int)rv.x;
        const float v = __uint_as_float(rv.y);
        const float a = __uint_as_float(((unsigned int)*(const unsigned short*)(hw4 + c * 16 + f)) << 16);
        acc = fmaf(v, a, acc);
    }
    acc += __shfl_xor(acc, 16);
    acc += __shfl_xor(acc, 32);
    acc += b4[f];
    float m = acc;
#pragma unroll
    for (int off = 1; off < 16; off <<= 1) m = fmaxf(m, __shfl_xor(m, off));
    const float ex = __expf(acc - m);
    float sum = ex;
#pragma unroll
    for (int off = 1; off < 16; off <<= 1) sum += __shfl_xor(sum, off);
    const float res = acc - m - __logf(sum);
    if (lane < 16) out[wid * 16 + f] = res;
}

extern "C" void kernel_launch(void* const* d_in, const int* in_sizes, int n_in,
                              void* d_out, int out_size, void* d_ws, size_t ws_size,
                              hipStream_t stream) {
    const float* x        = (const float*)d_in[0];
    const float* edge_val = (const float*)d_in[1];
    const float* W1       = (const float*)d_in[2];
    const float* b1       = (const float*)d_in[3];
    const float* W4       = (const float*)d_in[4];
    const float* b4       = (const float*)d_in[5];
    const int*   edge_row = (const int*)d_in[6];
    const int*   edge_col = (const int*)d_in[7];
    float* out = (float*)d_out;

    char* ws = (char*)d_ws;
    size_t off = 0;
    auto alloc = [&](size_t bytes) -> void* {
        void* p = ws + off;
        off = (off + bytes + 255) & ~(size_t)255;
        return p;
    };
    unsigned short* xw1 = (unsigned short*)alloc((size_t)NN * 128 * 2);  // 25.6 MB bf16
    float* h            = (float*)alloc((size_t)NN * 128 * 4);           // 51.2 MB
    unsigned short* hw4 = (unsigned short*)alloc((size_t)NN * 16 * 2);   // 3.2 MB bf16
    int*   bcnt         = (int*)alloc((size_t)NBUK * 4);                 // 50 KB
    int*   boff         = (int*)alloc((size_t)(NBUK + 1) * 4);
    int*   bcur         = (int*)alloc((size_t)NBUK * 4);
    int*   row_start    = (int*)alloc((size_t)(NN + 1) * 4);
    uint2* tmp          = (uint2*)alloc((size_t)NE * 8);                 // 25.6 MB
    uint2* recs         = (uint2*)alloc((size_t)NE * 8);                 // 25.6 MB

    hipMemsetAsync(bcnt, 0, (size_t)NBUK * 4, stream);

    k_gemm1<<<NN / 32, 256, 0, stream>>>(x, W1, xw1);
    k_bhist<<<(NE / 4 + 255) / 256, 256, 0, stream>>>((const int4*)edge_row, bcnt);
    k_bscan<<<1, 256, 0, stream>>>(bcnt, boff, bcur);
    k_bscatter<<<(NE / 4 + 255) / 256, 256, 0, stream>>>((const int4*)edge_row,
                                                         (const int4*)edge_col,
                                                         (const float4*)edge_val,
                                                         bcur, tmp);
    k_bfinal<<<NBUK, 256, 0, stream>>>(tmp, boff, recs, row_start);
    k_spmm1<<<(NN + 3) / 4, 256, 0, stream>>>((const unsigned int*)xw1, row_start, recs, b1, h);
    k_gemm2<<<(NN + 15) / 16, 256, 0, stream>>>(h, W4, hw4);
    k_spmm2<<<(NN + 3) / 4, 256, 0, stream>>>((const __hip_bfloat16*)hw4, row_start, recs, b4, out);
}

// Round 5
// 526.105 us; speedup vs baseline: 1.5042x; 1.5042x over previous
//
#include <hip/hip_runtime.h>
#include <hip/hip_bf16.h>

// Problem constants (fixed by reference)
constexpr int NN = 100000;   // nodes
constexpr int NE = 3200000;  // edges
constexpr int NWG = 256;               // chunks for count/place
constexpr int CHUNK = NE / NWG;        // 12500 edges per WG
constexpr int CHUNK4 = CHUNK / 4;      // 3125 int4s per WG
constexpr int NBUK1 = (NN + 511) / 512;  // 196 coarse buckets (rows >> 9)

__device__ __forceinline__ unsigned short f2bf(float f) {
    unsigned int u = __float_as_uint(f);
    unsigned int r = (u + 0x7fffu + ((u >> 16) & 1u)) >> 16;   // RNE
    return (unsigned short)r;
}

// ---------------- GEMM1: xw1 = bf16(x @ W1)  [NN,128]x[128,128] ----------------
__global__ __launch_bounds__(256) void k_gemm1(const float* __restrict__ x,
                                               const float* __restrict__ W,
                                               unsigned short* __restrict__ y) {
    __shared__ float ws_[128 * 128];   // 64 KB: whole W1
    __shared__ float xs[8][128];       // 8 staged rows
    const int t = threadIdx.x;
    for (int i = t; i < 128 * 128; i += 256) ws_[i] = W[i];

    const int rowg = t >> 5;          // 0..7 (row within sub-tile)
    const int cq   = (t & 31) * 4;    // 4 output cols
    const int row0 = blockIdx.x * 32;

    for (int rs = 0; rs < 32; rs += 8) {
        __syncthreads();
        {   // stage 8 rows (1024 floats) as 256 float4s
            const int r  = t >> 5;
            const int c4 = (t & 31) * 4;
            const int row = row0 + rs + r;
            float4 val = (row < NN) ? *(const float4*)(x + row * 128 + c4)
                                    : make_float4(0.f, 0.f, 0.f, 0.f);
            *(float4*)(&xs[r][c4]) = val;
        }
        __syncthreads();
        float4 acc = make_float4(0.f, 0.f, 0.f, 0.f);
#pragma unroll
        for (int k = 0; k < 128; ++k) {
            const float xv = xs[rowg][k];
            const float4 wv = *(const float4*)(&ws_[k * 128 + cq]);
            acc.x = fmaf(xv, wv.x, acc.x);
            acc.y = fmaf(xv, wv.y, acc.y);
            acc.z = fmaf(xv, wv.z, acc.z);
            acc.w = fmaf(xv, wv.w, acc.w);
        }
        const int row = row0 + rs + rowg;
        if (row < NN) {
            ushort4 o;
            o.x = f2bf(acc.x); o.y = f2bf(acc.y);
            o.z = f2bf(acc.z); o.w = f2bf(acc.w);
            *(ushort4*)(y + row * 128 + cq) = o;   // 8B store
        }
    }
}

// ---------------- CSR build: WG-exclusive counting sort ----------------
// coarse bucket = row >> 9 (512 rows). tmp record: x = (lrow<<17)|col, y = val.

// 1) per-WG bucket histogram of its contiguous chunk
__global__ __launch_bounds__(256) void k_count(const int4* __restrict__ erow4,
                                               int* __restrict__ cnt_tbl) {
    __shared__ int hist[NBUK1];
    const int t = threadIdx.x, wg = blockIdx.x;
    for (int i = t; i < NBUK1; i += 256) hist[i] = 0;
    __syncthreads();
    const int end4 = (wg + 1) * CHUNK4;
    for (int i4 = wg * CHUNK4 + t; i4 < end4; i4 += 256) {
        const int4 r = erow4[i4];
        atomicAdd(&hist[r.x >> 9], 1);
        atomicAdd(&hist[r.y >> 9], 1);
        atomicAdd(&hist[r.z >> 9], 1);
        atomicAdd(&hist[r.w >> 9], 1);
    }
    __syncthreads();
    for (int i = t; i < NBUK1; i += 256) cnt_tbl[wg * NBUK1 + i] = hist[i];
}

// 2) exact offsets: bucket bases + per-(wg,bucket) cursors (single WG)
__global__ __launch_bounds__(256) void k_scan2(const int* __restrict__ cnt_tbl,
                                               int* __restrict__ off_tbl,
                                               int* __restrict__ boff) {
    __shared__ int sd[256];
    const int t = threadIdx.x;
    int tot = 0;
    if (t < NBUK1)
        for (int wg = 0; wg < NWG; ++wg) tot += cnt_tbl[wg * NBUK1 + t];
    sd[t] = tot;
    __syncthreads();
    for (int off = 1; off < 256; off <<= 1) {
        int a = sd[t];
        int b = (t >= off) ? sd[t - off] : 0;
        __syncthreads();
        sd[t] = a + b;
        __syncthreads();
    }
    const int base = sd[t] - tot;   // exclusive bucket base
    if (t < NBUK1) {
        boff[t] = base;
        int run = base;
        for (int wg = 0; wg < NWG; ++wg) {
            off_tbl[wg * NBUK1 + t] = run;
            run += cnt_tbl[wg * NBUK1 + t];
        }
    }
    if (t == 0) boff[NBUK1] = NE;
}

// 3) scatter into exact per-WG contiguous runs (single-WG-owned lines)
__global__ __launch_bounds__(256) void k_place(const int4* __restrict__ erow4,
                                               const int4* __restrict__ ecol4,
                                               const float4* __restrict__ eval4,
                                               const int* __restrict__ off_tbl,
                                               uint2* __restrict__ tmp) {
    __shared__ int cur[NBUK1];
    const int t = threadIdx.x, wg = blockIdx.x;
    for (int i = t; i < NBUK1; i += 256) cur[i] = off_tbl[wg * NBUK1 + i];
    __syncthreads();
    const int end4 = (wg + 1) * CHUNK4;
    for (int i4 = wg * CHUNK4 + t; i4 < end4; i4 += 256) {
        const int4 r = erow4[i4];
        const int4 c = ecol4[i4];
        const float4 v = eval4[i4];
        int p;
        p = atomicAdd(&cur[r.x >> 9], 1);
        tmp[p] = make_uint2(((unsigned)(r.x & 511) << 17) | (unsigned)c.x, __float_as_uint(v.x));
        p = atomicAdd(&cur[r.y >> 9], 1);
        tmp[p] = make_uint2(((unsigned)(r.y & 511) << 17) | (unsigned)c.y, __float_as_uint(v.y));
        p = atomicAdd(&cur[r.z >> 9], 1);
        tmp[p] = make_uint2(((unsigned)(r.z & 511) << 17) | (unsigned)c.z, __float_as_uint(v.z));
        p = atomicAdd(&cur[r.w >> 9], 1);
        tmp[p] = make_uint2(((unsigned)(r.w & 511) << 17) | (unsigned)c.w, __float_as_uint(v.w));
    }
}

// 4) one WG per coarse bucket: row histogram+scan -> row_start, reorder to final CSR
__global__ __launch_bounds__(256) void k_sort2(const uint2* __restrict__ tmp,
                                               const int* __restrict__ boff,
                                               uint2* __restrict__ recs,
                                               int* __restrict__ row_start) {
    __shared__ int hist[512];
    __shared__ int cur[512];
    __shared__ int sd[256];
    const int b = blockIdx.x, t = threadIdx.x;
    const int base = boff[b];
    const int n = boff[b + 1] - base;
    hist[t] = 0; hist[t + 256] = 0;
    __syncthreads();
    for (int i = t; i < n; i += 256)
        atomicAdd(&hist[tmp[base + i].x >> 17], 1);
    __syncthreads();
    const int h0 = hist[2 * t], h1 = hist[2 * t + 1];
    const int pairsum = h0 + h1;
    sd[t] = pairsum;
    __syncthreads();
    for (int off = 1; off < 256; off <<= 1) {
        int a = sd[t];
        int bb = (t >= off) ? sd[t - off] : 0;
        __syncthreads();
        sd[t] = a + bb;
        __syncthreads();
    }
    const int e0 = sd[t] - pairsum;   // exclusive within bucket
    const int e1 = e0 + h0;
    cur[2 * t] = base + e0;
    cur[2 * t + 1] = base + e1;
    const int gr0 = b * 512 + 2 * t;
    if (gr0 < NN)     row_start[gr0] = base + e0;
    if (gr0 + 1 < NN) row_start[gr0 + 1] = base + e1;
    if (b == 0 && t == 0) row_start[NN] = NE;
    __syncthreads();
    for (int i = t; i < n; i += 256) {
        const uint2 rc = tmp[base + i];
        const int lr = rc.x >> 17;
        const int pos = atomicAdd(&cur[lr], 1);
        recs[pos] = make_uint2(rc.x & 0x1FFFFu, rc.y);
    }
}

// ---------------- SpMM1 + bias + ReLU: h = relu(A @ xw1 + b1) ----------------
// xw1 is bf16 [NN,128]: row = 64 uints (2 feats each). Lane handles feats 2*lane, 2*lane+1.
__global__ __launch_bounds__(256) void k_spmm1(const unsigned int* __restrict__ xw1u,
                                               const int* __restrict__ row_start,
                                               const uint2* __restrict__ recs,
                                               const float* __restrict__ b1,
                                               float* __restrict__ h) {
    const int wid = (blockIdx.x * 256 + threadIdx.x) >> 6;   // one wave per node
    const int lane = threadIdx.x & 63;
    if (wid >= NN) return;
    const int s = row_start[wid], e = row_start[wid + 1];
    float2 acc = make_float2(0.f, 0.f);
    for (int base = s; base < e; base += 64) {
        const int n = min(64, e - base);
        uint2 rv = make_uint2(0u, 0u);
        if (lane < n) rv = recs[base + lane];
        int j = 0;
        for (; j + 2 <= n; j += 2) {
            const int c0 = __shfl((int)rv.x, j), c1 = __shfl((int)rv.x, j + 1);
            const float v0 = __uint_as_float((unsigned int)__shfl((int)rv.y, j));
            const float v1 = __uint_as_float((unsigned int)__shfl((int)rv.y, j + 1));
            const unsigned int u0 = xw1u[c0 * 64 + lane];
            const unsigned int u1 = xw1u[c1 * 64 + lane];
            acc.x = fmaf(v0, __uint_as_float(u0 << 16), acc.x);
            acc.y = fmaf(v0, __uint_as_float(u0 & 0xffff0000u), acc.y);
            acc.x = fmaf(v1, __uint_as_float(u1 << 16), acc.x);
            acc.y = fmaf(v1, __uint_as_float(u1 & 0xffff0000u), acc.y);
        }
        if (j < n) {
            const int c0 = __shfl((int)rv.x, j);
            const float v0 = __uint_as_float((unsigned int)__shfl((int)rv.y, j));
            const unsigned int u0 = xw1u[c0 * 64 + lane];
            acc.x = fmaf(v0, __uint_as_float(u0 << 16), acc.x);
            acc.y = fmaf(v0, __uint_as_float(u0 & 0xffff0000u), acc.y);
        }
    }
    const float2 bb = *(const float2*)(b1 + (lane << 1));
    acc.x = fmaxf(acc.x + bb.x, 0.f);
    acc.y = fmaxf(acc.y + bb.y, 0.f);
    *(float2*)(h + wid * 128 + (lane << 1)) = acc;
}

// ---------------- GEMM2: hw4 = bf16(h @ W4)  [NN,128]x[128,16] ----------------
__global__ __launch_bounds__(256) void k_gemm2(const float* __restrict__ h,
                                               const float* __restrict__ W4,
                                               unsigned short* __restrict__ y) {
    __shared__ float w4s[128 * 16];
    __shared__ float hs[16 * 132];   // padded
    const int t = threadIdx.x;
    for (int i = t; i < 128 * 16; i += 256) w4s[i] = W4[i];
    const int row0 = blockIdx.x * 16;
    for (int idx4 = t; idx4 < 512; idx4 += 256) {   // 512 float4s = 16 rows
        const int r = idx4 >> 5;
        const int c4 = (idx4 & 31) * 4;
        const int row = row0 + r;
        float4 v = (row < NN) ? *(const float4*)(h + row * 128 + c4)
                              : make_float4(0.f, 0.f, 0.f, 0.f);
        *(float4*)(&hs[r * 132 + c4]) = v;
    }
    __syncthreads();
    const int r = t >> 4, c = t & 15;
    float acc = 0.f;
#pragma unroll
    for (int k = 0; k < 128; ++k) acc = fmaf(hs[r * 132 + k], w4s[k * 16 + c], acc);
    const int row = row0 + r;
    if (row < NN) y[row * 16 + c] = f2bf(acc);
}

// ---------------- SpMM2 + bias + log_softmax ----------------
// hw4 is bf16 [NN,16] = 32B rows (3.2 MB: mostly L2-resident)
__global__ __launch_bounds__(256) void k_spmm2(const __hip_bfloat16* __restrict__ hw4,
                                               const int* __restrict__ row_start,
                                               const uint2* __restrict__ recs,
                                               const float* __restrict__ b4,
                                               float* __restrict__ out) {
    const int wid = (blockIdx.x * 256 + threadIdx.x) >> 6;   // one wave per node
    const int lane = threadIdx.x & 63;
    if (wid >= NN) return;
    const int f = lane & 15, g = lane >> 4;   // 4 edges in parallel
    const int s = row_start[wid], e = row_start[wid + 1];
    float acc = 0.f;
    for (int base = s + g; base < e; base += 4) {
        const uint2 rv = recs[base];
        const int c = (int)rv.x;
        const float v = __uint_as_float(rv.y);
        const float a = __uint_as_float(((unsigned int)*(const unsigned short*)(hw4 + c * 16 + f)) << 16);
        acc = fmaf(v, a, acc);
    }
    acc += __shfl_xor(acc, 16);
    acc += __shfl_xor(acc, 32);
    acc += b4[f];
    float m = acc;
#pragma unroll
    for (int off = 1; off < 16; off <<= 1) m = fmaxf(m, __shfl_xor(m, off));
    const float ex = __expf(acc - m);
    float sum = ex;
#pragma unroll
    for (int off = 1; off < 16; off <<= 1) sum += __shfl_xor(sum, off);
    const float res = acc - m - __logf(sum);
    if (lane < 16) out[wid * 16 + f] = res;
}

extern "C" void kernel_launch(void* const* d_in, const int* in_sizes, int n_in,
                              void* d_out, int out_size, void* d_ws, size_t ws_size,
                              hipStream_t stream) {
    const float* x        = (const float*)d_in[0];
    const float* edge_val = (const float*)d_in[1];
    const float* W1       = (const float*)d_in[2];
    const float* b1       = (const float*)d_in[3];
    const float* W4       = (const float*)d_in[4];
    const float* b4       = (const float*)d_in[5];
    const int*   edge_row = (const int*)d_in[6];
    const int*   edge_col = (const int*)d_in[7];
    float* out = (float*)d_out;

    char* ws = (char*)d_ws;
    size_t off = 0;
    auto alloc = [&](size_t bytes) -> void* {
        void* p = ws + off;
        off = (off + bytes + 255) & ~(size_t)255;
        return p;
    };
    unsigned short* xw1 = (unsigned short*)alloc((size_t)NN * 128 * 2);  // 25.6 MB bf16
    float* h            = (float*)alloc((size_t)NN * 128 * 4);           // 51.2 MB
    unsigned short* hw4 = (unsigned short*)alloc((size_t)NN * 16 * 2);   // 3.2 MB bf16
    int*   cnt_tbl      = (int*)alloc((size_t)NWG * NBUK1 * 4);          // 200 KB
    int*   off_tbl      = (int*)alloc((size_t)NWG * NBUK1 * 4);          // 200 KB
    int*   boff         = (int*)alloc((size_t)(NBUK1 + 1) * 4);
    int*   row_start    = (int*)alloc((size_t)(NN + 1) * 4);
    uint2* tmp          = (uint2*)alloc((size_t)NE * 8);                 // 25.6 MB
    uint2* recs         = (uint2*)alloc((size_t)NE * 8);                 // 25.6 MB

    k_gemm1<<<NN / 32, 256, 0, stream>>>(x, W1, xw1);
    k_count<<<NWG, 256, 0, stream>>>((const int4*)edge_row, cnt_tbl);
    k_scan2<<<1, 256, 0, stream>>>(cnt_tbl, off_tbl, boff);
    k_place<<<NWG, 256, 0, stream>>>((const int4*)edge_row, (const int4*)edge_col,
                                     (const float4*)edge_val, off_tbl, tmp);
    k_sort2<<<NBUK1, 256, 0, stream>>>(tmp, boff, recs, row_start);
    k_spmm1<<<(NN + 3) / 4, 256, 0, stream>>>((const unsigned int*)xw1, row_start, recs, b1, h);
    k_gemm2<<<(NN + 15) / 16, 256, 0, stream>>>(h, W4, hw4);
    k_spmm2<<<(NN + 3) / 4, 256, 0, stream>>>((const __hip_bfloat16*)hw4, row_start, recs, b4, out);
}